// Round 9
// baseline (398.164 us; speedup 1.0000x reference)
//
#include <hip/hip_runtime.h>

// DynamicGCN: x[100000,384] fp32 -> Linear(384,64) -> GCNConv(64,64) -> ReLU -> GCNConv(64,64)
// Round 15 (pipeline C): atomics never share a dispatch with the GEMM; scale
// folded into the GEMM epilogue; raw-w records (fill reads no deg).
//   D0 memset  : deg=0, count=0 (800 KB)
//   D1 degfill : blocks 0..3124 deg atomics; blocks 3125..6249 fill {src, w}
//   D2 gemmscale: ts = bf16( rsqrt(deg+1) * (x@Wm + bm) )  (16KB LDS, 3 chunks)
//   D3 g1gemm  : Atile = rsd_d*(SUM w*ts[src] + ts[dst]); aggb = rsd_d*relu(Atile@W1+b1)
//   D4 g2gemm  : out = [rsd_d*(SUM w*aggb[src] + aggb[dst])] @ W2 + b2
// Gathers at measured random-line floor (~220us); preprocessing restructured.

#define NN 100000
#define NE 800000
#define BC 32          // bucket capacity per dst row (16 int4); P(Poisson(8)>32) ~ 1e-12

typedef unsigned short u16;
typedef __attribute__((ext_vector_type(8))) short short8;   // 8 bf16 (MFMA A/B frag)
typedef __attribute__((ext_vector_type(4))) float f4;       // MFMA C/D frag
typedef __attribute__((ext_vector_type(8))) unsigned short u16x8;

__device__ __forceinline__ u16 f2b(float f) {   // RNE fp32 -> bf16
    unsigned int x = __float_as_uint(f);
    x += 0x7fffu + ((x >> 16) & 1u);
    return (u16)(x >> 16);
}
__device__ __forceinline__ float b2f(u16 u) {
    return __uint_as_float(((unsigned int)u) << 16);
}

// ---- D1: blocks 0..3124 deg atomics; blocks 3125..6249 fill {src, raw w} --
// Separate blocks (not same thread: R8 showed in-thread atomic pairs serialize).
__global__ __launch_bounds__(256) void degfill_k(const int* __restrict__ ei,
                                                 const float* __restrict__ ew,
                                                 float* __restrict__ deg,
                                                 int* __restrict__ count,
                                                 int2* __restrict__ e2) {
    int tid = threadIdx.x, bid = blockIdx.x;
    if (bid < 3125) {                           // deg: 3125*256 == NE exact
        int e = bid * 256 + tid;
        atomicAdd(&deg[ei[NE + e]], ew[e]);
        return;
    }
    int e = (bid - 3125) * 256 + tid;           // fill: no deg dependency (raw w)
    int src = ei[e];
    int dst = ei[NE + e];
    int pos = atomicAdd(&count[dst], 1);
    if (pos < BC)                               // effectively never
        e2[(size_t)dst * BC + pos] = make_int2(src, __float_as_int(ew[e]));
}

// ---- D2: ts = bf16( rsqrt(deg+1) * (x@Wm + bm) ), 16KB LDS, 3 chunks ------
__global__ __launch_bounds__(256) void gemmscale_k(const float* __restrict__ x,
                                                   const float* __restrict__ Wm,
                                                   const float* __restrict__ bm,
                                                   const float* __restrict__ deg,
                                                   u16* __restrict__ ts) {
    __shared__ u16 Blds[4 * 256 * 8];           // 16 KB
    int tid = threadIdx.x, bid = blockIdx.x;
    int wave = tid >> 6, lane = tid & 63;
    int rowtile = bid * 4 + wave;
    bool act = rowtile < 6250;
    int rowbase = (act ? rowtile : 6249) * 16;
    int m = lane & 15, quad = lane >> 4;

    f4 acc[4];
#pragma unroll
    for (int ct = 0; ct < 4; ct++) acc[ct] = 0.0f;
    const short8* Bfrag = (const short8*)Blds;

#pragma unroll
    for (int chunk = 0; chunk < 3; chunk++) {
        for (int idx = tid; idx < 4 * 256; idx += 256) {
            int ktl = idx >> 8, rem = idx & 255;
            int ct = rem >> 6, ln = rem & 63;
            int kb = (chunk * 4 + ktl) * 32 + (ln >> 4) * 8;
            int col = ct * 16 + (ln & 15);
#pragma unroll
            for (int j = 0; j < 8; j++)
                Blds[idx * 8 + j] = f2b(Wm[(size_t)(kb + j) * 64 + col]);
        }
        __syncthreads();
#pragma unroll
        for (int ktl = 0; ktl < 4; ktl++) {
            const f4* p = (const f4*)&x[(size_t)(rowbase + m) * 384 + (chunk * 4 + ktl) * 32 + quad * 8];
            f4 v0 = p[0], v1 = p[1];
            short8 af;
#pragma unroll
            for (int j = 0; j < 4; j++) {
                af[j]     = (short)f2b(v0[j]);
                af[4 + j] = (short)f2b(v1[j]);
            }
#pragma unroll
            for (int ct = 0; ct < 4; ct++)
                acc[ct] = __builtin_amdgcn_mfma_f32_16x16x32_bf16(af, Bfrag[(ktl * 4 + ct) * 64 + lane], acc[ct], 0, 0, 0);
        }
        __syncthreads();
    }

    if (act) {
        float rsd[4];                           // rsqrt(deg+1) for my 4 output rows
#pragma unroll
        for (int r = 0; r < 4; r++)
            rsd[r] = rsqrtf(deg[rowbase + quad * 4 + r] + 1.0f);
#pragma unroll
        for (int ct = 0; ct < 4; ct++) {
            int col = ct * 16 + m;
            float bmv = bm[col];
#pragma unroll
            for (int r = 0; r < 4; r++)
                ts[(size_t)(rowbase + quad * 4 + r) * 64 + col] = f2b(rsd[r] * (acc[ct][r] + bmv));
        }
    }
}

// ---- gather core (raw w): 8 threads/row, 8 ch; unconditional paired int4
// loads, value-side masking (invalid -> src=dst, c=0; addresses in-row).
__device__ __forceinline__ void gatherR(const int2* __restrict__ eb, int cntv, int dst,
                                        const u16* __restrict__ hb, int ch,
                                        float* __restrict__ acc) {
    const int4* eb4 = (const int4*)eb;          // 16 int4 per bucket row
    for (int i = 0; i < cntv; i += 8) {
        int4 q[4];
#pragma unroll
        for (int p = 0; p < 4; p++) q[p] = eb4[(i >> 1) + p];
        int s[8];
        float c[8];
#pragma unroll
        for (int p = 0; p < 4; p++) {
            int t0 = i + 2 * p;
            bool v0 = t0 < cntv, v1 = (t0 + 1) < cntv;
            s[2 * p]     = v0 ? q[p].x : dst;
            c[2 * p]     = v0 ? __int_as_float(q[p].y) : 0.0f;
            s[2 * p + 1] = v1 ? q[p].z : dst;
            c[2 * p + 1] = v1 ? __int_as_float(q[p].w) : 0.0f;
        }
        u16x8 hv[8];
#pragma unroll
        for (int t = 0; t < 8; t++)
            hv[t] = *(const u16x8*)&hb[(size_t)s[t] * 64 + ch * 8];
#pragma unroll
        for (int t = 0; t < 8; t++) {
#pragma unroll
            for (int j = 0; j < 8; j++)
                acc[j] = fmaf(c[t], b2f(hv[t][j]), acc[j]);
        }
    }
}

__device__ __forceinline__ void fillW(u16* Wlds, const float* __restrict__ W, int tid) {
    for (int idx = tid; idx < 2 * 256; idx += 256) {
        int kt = idx >> 8, rem = idx & 255;
        int ct = rem >> 6, ln = rem & 63;
        int kb = kt * 32 + (ln >> 4) * 8;
        int col = ct * 16 + (ln & 15);
#pragma unroll
        for (int j = 0; j < 8; j++)
            Wlds[idx * 8 + j] = f2b(W[(size_t)(kb + j) * 64 + col]);
    }
}

// ---- D3 g1gemm: Atile = rsd_d*(gather + self); aggb = rsd_d*relu(Atile@W1+b1)
__global__ __launch_bounds__(256) void g1gemm_k(const int2* __restrict__ e2,
                                                const int* __restrict__ count,
                                                const float* __restrict__ deg,
                                                const u16* __restrict__ ts,
                                                const float* __restrict__ W1,
                                                const float* __restrict__ b1,
                                                u16* __restrict__ aggb) {
    __shared__ u16 Wlds[4096];                  // 8 KB swizzled W1 frags
    __shared__ u16 Atile[32][72];               // 32x64 bf16, +8 pad
    __shared__ float rsds[32];
    int tid = threadIdx.x;
    fillW(Wlds, W1, tid);

    int rt = tid >> 3, ch = tid & 7;
    int dst = blockIdx.x * 32 + rt;             // grid exact: 3125*32 == NN
    int cntv = min(count[dst], BC);
    float rsdd = rsqrtf(deg[dst] + 1.0f);
    u16x8 hs = *(const u16x8*)&ts[(size_t)dst * 64 + ch * 8];

    float acc[8] = {0, 0, 0, 0, 0, 0, 0, 0};
    gatherR(&e2[(size_t)dst * BC], cntv, dst, ts, ch, acc);

    u16x8 o;
#pragma unroll
    for (int j = 0; j < 8; j++)
        o[j] = f2b(rsdd * (acc[j] + b2f(hs[j])));
    *(u16x8*)&Atile[rt][ch * 8] = o;
    if (ch == 0) rsds[rt] = rsdd;
    __syncthreads();

    if (tid >= 128) return;                     // waves 0,1: Atile@W1 + b1, relu, x rsd
    int wave = tid >> 6, lane = tid & 63;
    int m = lane & 15, quad = lane >> 4;
    int rowoff = wave * 16;
    f4 cacc[4];
#pragma unroll
    for (int ct = 0; ct < 4; ct++) cacc[ct] = 0.0f;
    const short8* Bfrag = (const short8*)Wlds;
#pragma unroll
    for (int kt = 0; kt < 2; kt++) {
        short8 af = *(const short8*)&Atile[rowoff + m][kt * 32 + quad * 8];
#pragma unroll
        for (int ct = 0; ct < 4; ct++)
            cacc[ct] = __builtin_amdgcn_mfma_f32_16x16x32_bf16(af, Bfrag[(kt * 4 + ct) * 64 + lane], cacc[ct], 0, 0, 0);
    }
    int rowbase = blockIdx.x * 32 + rowoff;
#pragma unroll
    for (int ct = 0; ct < 4; ct++) {
        int col = ct * 16 + m;
        float bb = b1[col];
#pragma unroll
        for (int rr = 0; rr < 4; rr++) {
            int rl = rowoff + quad * 4 + rr;
            float v = fmaxf(cacc[ct][rr] + bb, 0.0f);
            aggb[(size_t)(rowbase + quad * 4 + rr) * 64 + col] = f2b(rsds[rl] * v);
        }
    }
}

// ---- D4 g2gemm: out = [rsd_d*(gather + self)]@W2 + b2, fp32 ---------------
__global__ __launch_bounds__(256) void g2gemm_k(const int2* __restrict__ e2,
                                                const int* __restrict__ count,
                                                const float* __restrict__ deg,
                                                const u16* __restrict__ aggb,
                                                const float* __restrict__ W2,
                                                const float* __restrict__ b2,
                                                float* __restrict__ out) {
    __shared__ u16 Wlds[4096];                  // 8 KB swizzled W2 frags
    __shared__ u16 Atile[32][72];               // 32x64 bf16, +8 pad
    int tid = threadIdx.x;
    fillW(Wlds, W2, tid);

    int rt = tid >> 3, ch = tid & 7;
    int dst = blockIdx.x * 32 + rt;             // grid exact: 3125*32 == NN
    int cntv = min(count[dst], BC);
    float rsdd = rsqrtf(deg[dst] + 1.0f);
    u16x8 hs = *(const u16x8*)&aggb[(size_t)dst * 64 + ch * 8];

    float acc[8] = {0, 0, 0, 0, 0, 0, 0, 0};
    gatherR(&e2[(size_t)dst * BC], cntv, dst, aggb, ch, acc);

    u16x8 o;
#pragma unroll
    for (int j = 0; j < 8; j++)
        o[j] = f2b(rsdd * (acc[j] + b2f(hs[j])));
    *(u16x8*)&Atile[rt][ch * 8] = o;
    __syncthreads();

    if (tid >= 128) return;                     // waves 0,1 compute the MFMA
    int wave = tid >> 6, lane = tid & 63;
    int m = lane & 15, quad = lane >> 4;
    int rowoff = wave * 16;
    f4 cacc[4];
#pragma unroll
    for (int ct = 0; ct < 4; ct++) cacc[ct] = 0.0f;
    const short8* Bfrag = (const short8*)Wlds;
#pragma unroll
    for (int kt = 0; kt < 2; kt++) {
        short8 af = *(const short8*)&Atile[rowoff + m][kt * 32 + quad * 8];
#pragma unroll
        for (int ct = 0; ct < 4; ct++)
            cacc[ct] = __builtin_amdgcn_mfma_f32_16x16x32_bf16(af, Bfrag[(kt * 4 + ct) * 64 + lane], cacc[ct], 0, 0, 0);
    }
    int rowbase = blockIdx.x * 32 + rowoff;
#pragma unroll
    for (int ct = 0; ct < 4; ct++) {
        int col = ct * 16 + m;
        float bc = b2[col];
#pragma unroll
        for (int rr = 0; rr < 4; rr++)
            out[(size_t)(rowbase + quad * 4 + rr) * 64 + col] = cacc[ct][rr] + bc;
    }
}

extern "C" void kernel_launch(void* const* d_in, const int* in_sizes, int n_in,
                              void* d_out, int out_size, void* d_ws, size_t ws_size,
                              hipStream_t stream) {
    const float* x  = (const float*)d_in[0];
    const int*   ei = (const int*)d_in[1];
    const float* ew = (const float*)d_in[2];
    const float* Wm = (const float*)d_in[3];
    const float* bm = (const float*)d_in[4];
    const float* W1 = (const float*)d_in[5];
    const float* b1 = (const float*)d_in[6];
    const float* W2 = (const float*)d_in[7];
    const float* b2 = (const float*)d_in[8];
    float* out = (float*)d_out;

    // ws layout (offsets in bytes)
    char*  w     = (char*)d_ws;
    float* deg   = (float*)(w);                 // NN f32 (400 KB)
    int*   count = (int*)(w + 400000);          // NN i32 (contiguous with deg)
    int2*  e2    = (int2*)(w + (4u << 20));     // NN*BC int2 (25.6 MB)
    u16*   ts    = (u16*)(w + (32u << 20));     // NN*64 bf16 (12.8 MB)
    u16*   aggb  = (u16*)(w + (48u << 20));     // NN*64 bf16 (12.8 MB)

    // D0: zero deg+count (800 KB contiguous)
    hipMemsetAsync(w, 0, 800000, stream);
    // D1: deg atomics || raw-w fill (separate block ranges, no LDS)
    degfill_k<<<6250, 256, 0, stream>>>(ei, ew, deg, count, e2);
    // D2: ts = bf16( rsqrt(deg+1) * (x@Wm + bm) )  (GEMM alone, full occupancy)
    gemmscale_k<<<1563, 256, 0, stream>>>(x, Wm, bm, deg, ts);
    // D3: aggb = rsd_d * relu((rsd_d*(A_raw*ts + self))@W1 + b1)
    g1gemm_k<<<3125, 256, 0, stream>>>(e2, count, deg, ts, W1, b1, aggb);
    // D4: out = (rsd_d*(A_raw*aggb + self))@W2 + b2
    g2gemm_k<<<3125, 256, 0, stream>>>(e2, count, deg, aggb, W2, b2, out);
}

// Round 10
// 365.096 us; speedup vs baseline: 1.0906x; 1.0906x over previous
//
#include <hip/hip_runtime.h>

// DynamicGCN: x[100000,384] fp32 -> Linear(384,64) -> GCNConv(64,64) -> ReLU -> GCNConv(64,64)
// Round 16: deg atomic pass DELETED — deg summed from bucket rows (dense).
//   D0 memset  : count=0 (400 KB only)
//   D1 fillgemm: blocks 0..3124 fill {src, raw w} (count atomic + record; NO deg reads)
//                blocks 3125..4687 t32 = x@Wm + bm (fp32, 16KB LDS, 3 chunks)
//                (fill and gemm fully independent -> overlap, R7-verified pattern)
//   D2 degscale: per dst row: deg = sum(w in bucket row) [dense e2 read, shfl reduce];
//                rsd[dst] = rsqrt(deg+1); ts = bf16(rsd * t32 row)  (single rounding)
//   D3 g1gemm  : Atile = rsd_d*(SUM w*ts[src] + ts[dst]); aggb = rsd_d*relu(Atile@W1+b1)
//   D4 g2gemm  : out = [rsd_d*(SUM w*aggb[src] + aggb[dst])] @ W2 + b2
// Gathers at measured random-line floor (~220us, invariant over 5 structures).

#define NN 100000
#define NE 800000
#define BC 32          // bucket capacity per dst row (16 int4); P(Poisson(8)>32) ~ 1e-12

typedef unsigned short u16;
typedef __attribute__((ext_vector_type(8))) short short8;   // 8 bf16 (MFMA A/B frag)
typedef __attribute__((ext_vector_type(4))) float f4;       // MFMA C/D frag
typedef __attribute__((ext_vector_type(8))) unsigned short u16x8;

__device__ __forceinline__ u16 f2b(float f) {   // RNE fp32 -> bf16
    unsigned int x = __float_as_uint(f);
    x += 0x7fffu + ((x >> 16) & 1u);
    return (u16)(x >> 16);
}
__device__ __forceinline__ float b2f(u16 u) {
    return __uint_as_float(((unsigned int)u) << 16);
}

// ---- D1: blocks 0..3124 fill {src, raw w}; blocks 3125..4687 t32=x@Wm+bm --
__global__ __launch_bounds__(256) void fillgemm_k(const int* __restrict__ ei,
                                                  const float* __restrict__ ew,
                                                  int* __restrict__ count,
                                                  int2* __restrict__ e2,
                                                  const float* __restrict__ x,
                                                  const float* __restrict__ Wm,
                                                  const float* __restrict__ bm,
                                                  float* __restrict__ t32) {
    __shared__ u16 Blds[4 * 256 * 8];           // 16 KB
    int tid = threadIdx.x, bid = blockIdx.x;
    if (bid < 3125) {                           // fill: 3125*256 == NE exact
        int e = bid * 256 + tid;
        int src = ei[e];
        int dst = ei[NE + e];
        int pos = atomicAdd(&count[dst], 1);
        if (pos < BC)                           // effectively never
            e2[(size_t)dst * BC + pos] = make_int2(src, __float_as_int(ew[e]));
        return;
    }
    // ---- gemm: t32 = x[100000,384] @ Wm[384,64] + bm, fp32, 3 chunks ------
    int wave = tid >> 6, lane = tid & 63;
    int rowtile = (bid - 3125) * 4 + wave;
    bool act = rowtile < 6250;
    int rowbase = (act ? rowtile : 6249) * 16;
    int m = lane & 15, quad = lane >> 4;

    f4 acc[4];
#pragma unroll
    for (int ct = 0; ct < 4; ct++) acc[ct] = 0.0f;
    const short8* Bfrag = (const short8*)Blds;

#pragma unroll
    for (int chunk = 0; chunk < 3; chunk++) {
        for (int idx = tid; idx < 4 * 256; idx += 256) {
            int ktl = idx >> 8, rem = idx & 255;
            int ct = rem >> 6, ln = rem & 63;
            int kb = (chunk * 4 + ktl) * 32 + (ln >> 4) * 8;
            int col = ct * 16 + (ln & 15);
#pragma unroll
            for (int j = 0; j < 8; j++)
                Blds[idx * 8 + j] = f2b(Wm[(size_t)(kb + j) * 64 + col]);
        }
        __syncthreads();
#pragma unroll
        for (int ktl = 0; ktl < 4; ktl++) {
            const f4* p = (const f4*)&x[(size_t)(rowbase + m) * 384 + (chunk * 4 + ktl) * 32 + quad * 8];
            f4 v0 = p[0], v1 = p[1];
            short8 af;
#pragma unroll
            for (int j = 0; j < 4; j++) {
                af[j]     = (short)f2b(v0[j]);
                af[4 + j] = (short)f2b(v1[j]);
            }
#pragma unroll
            for (int ct = 0; ct < 4; ct++)
                acc[ct] = __builtin_amdgcn_mfma_f32_16x16x32_bf16(af, Bfrag[(ktl * 4 + ct) * 64 + lane], acc[ct], 0, 0, 0);
        }
        __syncthreads();
    }

    if (act) {
#pragma unroll
        for (int ct = 0; ct < 4; ct++) {
            int col = ct * 16 + m;
            float bmv = bm[col];
#pragma unroll
            for (int r = 0; r < 4; r++)
                t32[(size_t)(rowbase + quad * 4 + r) * 64 + col] = acc[ct][r] + bmv;
        }
    }
}

// ---- D2 degscale: deg from bucket row (dense), rsd table, ts = rsd*t32 ----
__global__ __launch_bounds__(256) void degscale_k(const int* __restrict__ count,
                                                  const int2* __restrict__ e2,
                                                  const float* __restrict__ t32,
                                                  float* __restrict__ rsdout,
                                                  u16* __restrict__ ts) {
    int tid = threadIdx.x;
    int rt = tid >> 3, ch = tid & 7;
    int dst = blockIdx.x * 32 + rt;             // grid exact: 3125*32 == NN
    int cnt = min(count[dst], BC);

    // this thread covers records 4*ch .. 4*ch+3 (two int4 = 4 int2 records)
    const int4* eb4 = (const int4*)&e2[(size_t)dst * BC];
    int4 a = eb4[2 * ch], b = eb4[2 * ch + 1];
    int base = 4 * ch;
    float s = 0.0f;
    if (base + 0 < cnt) s += __int_as_float(a.y);
    if (base + 1 < cnt) s += __int_as_float(a.w);
    if (base + 2 < cnt) s += __int_as_float(b.y);
    if (base + 3 < cnt) s += __int_as_float(b.w);
#pragma unroll
    for (int off = 1; off < 8; off <<= 1)       // reduce across the 8-lane group
        s += __shfl_xor(s, off);

    float rsd = rsqrtf(s + 1.0f);               // self-loop +1 folded
    if (ch == 0) rsdout[dst] = rsd;

    const f4* p = (const f4*)&t32[(size_t)dst * 64 + ch * 8];
    f4 v0 = p[0], v1 = p[1];
    u16x8 o;
#pragma unroll
    for (int j = 0; j < 4; j++) {
        o[j]     = f2b(rsd * v0[j]);
        o[4 + j] = f2b(rsd * v1[j]);
    }
    ((u16x8*)ts)[(size_t)dst * 8 + ch] = o;
}

// ---- gather core (raw w): 8 threads/row, 8 ch; unconditional paired int4
// loads, value-side masking (invalid -> src=dst, c=0; addresses in-row).
__device__ __forceinline__ void gatherR(const int2* __restrict__ eb, int cntv, int dst,
                                        const u16* __restrict__ hb, int ch,
                                        float* __restrict__ acc) {
    const int4* eb4 = (const int4*)eb;          // 16 int4 per bucket row
    for (int i = 0; i < cntv; i += 8) {
        int4 q[4];
#pragma unroll
        for (int p = 0; p < 4; p++) q[p] = eb4[(i >> 1) + p];
        int s[8];
        float c[8];
#pragma unroll
        for (int p = 0; p < 4; p++) {
            int t0 = i + 2 * p;
            bool v0 = t0 < cntv, v1 = (t0 + 1) < cntv;
            s[2 * p]     = v0 ? q[p].x : dst;
            c[2 * p]     = v0 ? __int_as_float(q[p].y) : 0.0f;
            s[2 * p + 1] = v1 ? q[p].z : dst;
            c[2 * p + 1] = v1 ? __int_as_float(q[p].w) : 0.0f;
        }
        u16x8 hv[8];
#pragma unroll
        for (int t = 0; t < 8; t++)
            hv[t] = *(const u16x8*)&hb[(size_t)s[t] * 64 + ch * 8];
#pragma unroll
        for (int t = 0; t < 8; t++) {
#pragma unroll
            for (int j = 0; j < 8; j++)
                acc[j] = fmaf(c[t], b2f(hv[t][j]), acc[j]);
        }
    }
}

__device__ __forceinline__ void fillW(u16* Wlds, const float* __restrict__ W, int tid) {
    for (int idx = tid; idx < 2 * 256; idx += 256) {
        int kt = idx >> 8, rem = idx & 255;
        int ct = rem >> 6, ln = rem & 63;
        int kb = kt * 32 + (ln >> 4) * 8;
        int col = ct * 16 + (ln & 15);
#pragma unroll
        for (int j = 0; j < 8; j++)
            Wlds[idx * 8 + j] = f2b(W[(size_t)(kb + j) * 64 + col]);
    }
}

// ---- D3 g1gemm: Atile = rsd_d*(gather + self); aggb = rsd_d*relu(Atile@W1+b1)
__global__ __launch_bounds__(256) void g1gemm_k(const int2* __restrict__ e2,
                                                const int* __restrict__ count,
                                                const float* __restrict__ rsd,
                                                const u16* __restrict__ ts,
                                                const float* __restrict__ W1,
                                                const float* __restrict__ b1,
                                                u16* __restrict__ aggb) {
    __shared__ u16 Wlds[4096];                  // 8 KB swizzled W1 frags
    __shared__ u16 Atile[32][72];               // 32x64 bf16, +8 pad
    __shared__ float rsds[32];
    int tid = threadIdx.x;
    fillW(Wlds, W1, tid);

    int rt = tid >> 3, ch = tid & 7;
    int dst = blockIdx.x * 32 + rt;             // grid exact: 3125*32 == NN
    int cntv = min(count[dst], BC);
    float rsdd = rsd[dst];
    u16x8 hs = *(const u16x8*)&ts[(size_t)dst * 64 + ch * 8];

    float acc[8] = {0, 0, 0, 0, 0, 0, 0, 0};
    gatherR(&e2[(size_t)dst * BC], cntv, dst, ts, ch, acc);

    u16x8 o;
#pragma unroll
    for (int j = 0; j < 8; j++)
        o[j] = f2b(rsdd * (acc[j] + b2f(hs[j])));
    *(u16x8*)&Atile[rt][ch * 8] = o;
    if (ch == 0) rsds[rt] = rsdd;
    __syncthreads();

    if (tid >= 128) return;                     // waves 0,1: Atile@W1 + b1, relu, x rsd
    int wave = tid >> 6, lane = tid & 63;
    int m = lane & 15, quad = lane >> 4;
    int rowoff = wave * 16;
    f4 cacc[4];
#pragma unroll
    for (int ct = 0; ct < 4; ct++) cacc[ct] = 0.0f;
    const short8* Bfrag = (const short8*)Wlds;
#pragma unroll
    for (int kt = 0; kt < 2; kt++) {
        short8 af = *(const short8*)&Atile[rowoff + m][kt * 32 + quad * 8];
#pragma unroll
        for (int ct = 0; ct < 4; ct++)
            cacc[ct] = __builtin_amdgcn_mfma_f32_16x16x32_bf16(af, Bfrag[(kt * 4 + ct) * 64 + lane], cacc[ct], 0, 0, 0);
    }
    int rowbase = blockIdx.x * 32 + rowoff;
#pragma unroll
    for (int ct = 0; ct < 4; ct++) {
        int col = ct * 16 + m;
        float bb = b1[col];
#pragma unroll
        for (int rr = 0; rr < 4; rr++) {
            int rl = rowoff + quad * 4 + rr;
            float v = fmaxf(cacc[ct][rr] + bb, 0.0f);
            aggb[(size_t)(rowbase + quad * 4 + rr) * 64 + col] = f2b(rsds[rl] * v);
        }
    }
}

// ---- D4 g2gemm: out = [rsd_d*(gather + self)]@W2 + b2, fp32 ---------------
__global__ __launch_bounds__(256) void g2gemm_k(const int2* __restrict__ e2,
                                                const int* __restrict__ count,
                                                const float* __restrict__ rsd,
                                                const u16* __restrict__ aggb,
                                                const float* __restrict__ W2,
                                                const float* __restrict__ b2,
                                                float* __restrict__ out) {
    __shared__ u16 Wlds[4096];                  // 8 KB swizzled W2 frags
    __shared__ u16 Atile[32][72];               // 32x64 bf16, +8 pad
    int tid = threadIdx.x;
    fillW(Wlds, W2, tid);

    int rt = tid >> 3, ch = tid & 7;
    int dst = blockIdx.x * 32 + rt;             // grid exact: 3125*32 == NN
    int cntv = min(count[dst], BC);
    float rsdd = rsd[dst];
    u16x8 hs = *(const u16x8*)&aggb[(size_t)dst * 64 + ch * 8];

    float acc[8] = {0, 0, 0, 0, 0, 0, 0, 0};
    gatherR(&e2[(size_t)dst * BC], cntv, dst, aggb, ch, acc);

    u16x8 o;
#pragma unroll
    for (int j = 0; j < 8; j++)
        o[j] = f2b(rsdd * (acc[j] + b2f(hs[j])));
    *(u16x8*)&Atile[rt][ch * 8] = o;
    __syncthreads();

    if (tid >= 128) return;                     // waves 0,1 compute the MFMA
    int wave = tid >> 6, lane = tid & 63;
    int m = lane & 15, quad = lane >> 4;
    int rowoff = wave * 16;
    f4 cacc[4];
#pragma unroll
    for (int ct = 0; ct < 4; ct++) cacc[ct] = 0.0f;
    const short8* Bfrag = (const short8*)Wlds;
#pragma unroll
    for (int kt = 0; kt < 2; kt++) {
        short8 af = *(const short8*)&Atile[rowoff + m][kt * 32 + quad * 8];
#pragma unroll
        for (int ct = 0; ct < 4; ct++)
            cacc[ct] = __builtin_amdgcn_mfma_f32_16x16x32_bf16(af, Bfrag[(kt * 4 + ct) * 64 + lane], cacc[ct], 0, 0, 0);
    }
    int rowbase = blockIdx.x * 32 + rowoff;
#pragma unroll
    for (int ct = 0; ct < 4; ct++) {
        int col = ct * 16 + m;
        float bc = b2[col];
#pragma unroll
        for (int rr = 0; rr < 4; rr++)
            out[(size_t)(rowbase + quad * 4 + rr) * 64 + col] = cacc[ct][rr] + bc;
    }
}

extern "C" void kernel_launch(void* const* d_in, const int* in_sizes, int n_in,
                              void* d_out, int out_size, void* d_ws, size_t ws_size,
                              hipStream_t stream) {
    const float* x  = (const float*)d_in[0];
    const int*   ei = (const int*)d_in[1];
    const float* ew = (const float*)d_in[2];
    const float* Wm = (const float*)d_in[3];
    const float* bm = (const float*)d_in[4];
    const float* W1 = (const float*)d_in[5];
    const float* b1 = (const float*)d_in[6];
    const float* W2 = (const float*)d_in[7];
    const float* b2 = (const float*)d_in[8];
    float* out = (float*)d_out;

    // ws layout (offsets in bytes)
    char*  w     = (char*)d_ws;
    int*   count = (int*)(w);                   // NN i32 (400 KB)
    float* rsd   = (float*)(w + (512 << 10));   // NN f32 dense
    int2*  e2    = (int2*)(w + (4u << 20));     // NN*BC int2 (25.6 MB)
    float* t32   = (float*)(w + (32u << 20));   // NN*64 f32 (25.6 MB)
    u16*   ts    = (u16*)(w + (64u << 20));     // NN*64 bf16 (12.8 MB)
    u16*   aggb  = (u16*)(w + (80u << 20));     // NN*64 bf16 (12.8 MB)

    // D0: zero count only (400 KB)
    hipMemsetAsync(w, 0, 400000, stream);
    // D1: fill raw records || t32 = x@Wm + bm   (fully independent)
    fillgemm_k<<<4688, 256, 0, stream>>>(ei, ew, count, e2, x, Wm, bm, t32);
    // D2: deg from buckets (dense) -> rsd table; ts = bf16(rsd * t32)
    degscale_k<<<3125, 256, 0, stream>>>(count, e2, t32, rsd, ts);
    // D3: aggb = rsd_d * relu((rsd_d*(A_raw*ts + self))@W1 + b1)
    g1gemm_k<<<3125, 256, 0, stream>>>(e2, count, rsd, ts, W1, b1, aggb);
    // D4: out = (rsd_d*(A_raw*aggb + self))@W2 + b2
    g2gemm_k<<<3125, 256, 0, stream>>>(e2, count, rsd, aggb, W2, b2, out);
}